// Round 1
// baseline (368.876 us; speedup 1.0000x reference)
//
#include <hip/hip_runtime.h>
#include <hip/hip_bf16.h>

// Problem constants (match reference)
constexpr int NE  = 8;     // experts
constexpr int T   = 2048;  // tokens
constexpr int IN  = 2048;  // reduction dim
constexpr int OUT = 2048;  // output dim
constexpr int GS  = 64;    // quant group size
constexpr int G   = IN / GS;

// Tile config
constexpr int BM = 128;
constexpr int BN = 128;
constexpr int BK = 64;            // == GS: one scale/zero per K-tile
constexpr int LDA = BK + 8;       // pad -> 2-way bank aliasing only (free)
constexpr int LDB = BK + 8;

using short8  = __attribute__((ext_vector_type(8))) short;
using floatx4 = __attribute__((ext_vector_type(4))) float;

__global__ __launch_bounds__(256, 2)
void hqq_grouped_gemm(const float* __restrict__ x,
                      const int*   __restrict__ qw,
                      const float* __restrict__ snz,   // [E][G][OUT][2]
                      const int*   __restrict__ tpe,   // [E]
                      float* __restrict__ out) {
    const int tid = threadIdx.x;
    const int e  = blockIdx.z;
    const int tm = blockIdx.y;
    const int n0 = blockIdx.x * BN;

    // expert row bounds from prefix sum (8 cached loads, wave-uniform)
    int b0 = 0;
    for (int i = 0; i < NE; ++i) {
        int c = tpe[i];
        if (i < e) b0 += c;
    }
    const int b1 = b0 + tpe[e];
    const int row0 = b0 + tm * BM;
    if (row0 >= b1) return;   // token tile past this expert's slice

    __shared__ __hip_bfloat16 As[BM][LDA];  // [m][k]
    __shared__ __hip_bfloat16 Bs[BN][LDB];  // TRANSPOSED: [n][k]

    floatx4 acc[4][4];
#pragma unroll
    for (int i = 0; i < 4; ++i)
#pragma unroll
        for (int j = 0; j < 4; ++j)
            acc[i][j] = (floatx4){0.f, 0.f, 0.f, 0.f};

    // A-stage mapping: fixed k-col group per thread, rows advance by 16
    const int a_c  = (tid & 15) * 4;   // k offset within tile (float4 granule)
    const int a_r0 = tid >> 4;         // row base (0..15)

    // B-stage mapping: fixed n per thread, two k-octet bases
    const int bn_ = tid & 127;             // n within tile
    const int bk0 = (tid >> 7) * 8;        // 0 or 8; pairs at +0,+16,+32,+48

    // wave / lane decomposition for MFMA
    const int lane = tid & 63;
    const int wid  = tid >> 6;
    const int wm = (wid >> 1) * 64;
    const int wn = (wid & 1) * 64;
    const int lm = lane & 15;
    const int lk = (lane >> 4) * 8;

    const int*    qbase  = qw + (size_t)e * IN * OUT + n0 + bn_;
    const float2* szbase = (const float2*)snz + (size_t)e * G * OUT + n0 + bn_;

    for (int k0 = 0; k0 < IN; k0 += BK) {
        // ---- stage A: x fp32 -> bf16 LDS, zero-pad invalid rows ----
#pragma unroll
        for (int it = 0; it < 8; ++it) {
            const int r   = a_r0 + it * 16;
            const int row = row0 + r;
            float4 v = {0.f, 0.f, 0.f, 0.f};
            if (row < b1)
                v = *(const float4*)(x + (size_t)row * IN + k0 + a_c);
            union { unsigned long long u; __hip_bfloat16 h[4]; } pa;
            pa.h[0] = __float2bfloat16(v.x);
            pa.h[1] = __float2bfloat16(v.y);
            pa.h[2] = __float2bfloat16(v.z);
            pa.h[3] = __float2bfloat16(v.w);
            *(unsigned long long*)&As[r][a_c] = pa.u;
        }

        // ---- stage B: int4(as int32) dequant -> bf16, transposed LDS ----
        const int g = k0 >> 6;                 // k0 / GS
        const float2 sz = szbase[(size_t)g * OUT];
        const float s = sz.x, z = sz.y;
#pragma unroll
        for (int p = 0; p < 4; ++p) {
            const int k8 = bk0 + p * 16;
            const int* qp = qbase + (size_t)(k0 + k8) * OUT;
            union { short8 v; __hip_bfloat16 h[8]; } pb;
#pragma unroll
            for (int j = 0; j < 8; ++j) {
                const int q = qp[(size_t)j * OUT];   // coalesced across lanes (n-contig)
                pb.h[j] = __float2bfloat16((float)(q - 8) * s + z);
            }
            *(short8*)&Bs[bn_][k8] = pb.v;           // one ds_write_b128
        }

        __syncthreads();

        // ---- MFMA over the K-tile ----
#pragma unroll
        for (int ks = 0; ks < BK; ks += 32) {
            short8 af[4], bfr[4];
#pragma unroll
            for (int i = 0; i < 4; ++i)
                af[i] = *(const short8*)&As[wm + i * 16 + lm][ks + lk];
#pragma unroll
            for (int j = 0; j < 4; ++j)
                bfr[j] = *(const short8*)&Bs[wn + j * 16 + lm][ks + lk];
#pragma unroll
            for (int i = 0; i < 4; ++i)
#pragma unroll
                for (int j = 0; j < 4; ++j)
                    acc[i][j] = __builtin_amdgcn_mfma_f32_16x16x32_bf16(
                        af[i], bfr[j], acc[i][j], 0, 0, 0);
        }

        __syncthreads();
    }

    // ---- epilogue: C/D layout col=lane&15, row=(lane>>4)*4+reg ----
    const int lq = (lane >> 4) * 4;
#pragma unroll
    for (int i = 0; i < 4; ++i) {
#pragma unroll
        for (int r = 0; r < 4; ++r) {
            const int row = row0 + wm + i * 16 + lq + r;
            if (row < b1) {
                float* op = out + (size_t)row * OUT + n0 + wn + lm;
#pragma unroll
                for (int j = 0; j < 4; ++j)
                    op[j * 16] = acc[i][j][r];
            }
        }
    }
}

extern "C" void kernel_launch(void* const* d_in, const int* in_sizes, int n_in,
                              void* d_out, int out_size, void* d_ws, size_t ws_size,
                              hipStream_t stream) {
    const float* x   = (const float*)d_in[0];
    const int*   qw  = (const int*)d_in[1];
    const float* snz = (const float*)d_in[2];
    const int*   tpe = (const int*)d_in[3];
    float* out = (float*)d_out;

    dim3 grid(OUT / BN, T / BM, NE);   // 16 x 16 x 8 = 2048 blocks, most exit early
    hqq_grouped_gemm<<<grid, 256, 0, stream>>>(x, qw, snz, tpe, out);
}

// Round 2
// 301.455 us; speedup vs baseline: 1.2237x; 1.2237x over previous
//
#include <hip/hip_runtime.h>
#include <hip/hip_bf16.h>

// Problem constants (match reference)
constexpr int NE  = 8;     // experts
constexpr int T   = 2048;  // tokens
constexpr int IN  = 2048;  // reduction dim
constexpr int OUT = 2048;  // output dim
constexpr int GS  = 64;    // quant group size
constexpr int G   = IN / GS;

// Tile config
constexpr int BM = 128;
constexpr int BN = 64;            // 64: 32 n-tiles -> 2x blocks vs R1
constexpr int BK = 64;            // == GS: one scale/zero per K-tile
constexpr int KSPLIT = 2;         // 2 k-halves per (m,n) tile -> 2x blocks
constexpr int KCH = IN / KSPLIT;  // 1024
constexpr int LDA = BK + 8;       // pad -> 2-way bank aliasing only (free, m136)
constexpr int LDB = BK + 8;

using short8  = __attribute__((ext_vector_type(8))) short;
using floatx4 = __attribute__((ext_vector_type(4))) float;

__global__ __launch_bounds__(256, 4)
void hqq_grouped_gemm(const float* __restrict__ x,
                      const int*   __restrict__ qw,
                      const float* __restrict__ snz,   // [E][G][OUT][2]
                      const int*   __restrict__ tpe,   // [E]
                      float* __restrict__ out) {
    const int tid = threadIdx.x;
    const int e   = blockIdx.z >> 1;
    const int kh  = blockIdx.z & 1;
    const int tm  = blockIdx.y;
    const int n0  = blockIdx.x * BN;

    // expert row bounds from prefix sum (8 cached loads, wave-uniform)
    int b0 = 0;
    for (int i = 0; i < NE; ++i) {
        int c = tpe[i];
        if (i < e) b0 += c;
    }
    const int b1 = b0 + tpe[e];
    const int row0 = b0 + tm * BM;
    if (row0 >= b1) return;   // token tile past this expert's slice

    __shared__ __hip_bfloat16 As[BM][LDA];  // [m][k]
    __shared__ __hip_bfloat16 Bs[BN][LDB];  // TRANSPOSED: [n][k]

    floatx4 acc[2][4];
#pragma unroll
    for (int i = 0; i < 2; ++i)
#pragma unroll
        for (int j = 0; j < 4; ++j)
            acc[i][j] = (floatx4){0.f, 0.f, 0.f, 0.f};

    // A-stage mapping: fixed k-col group per thread, rows advance by 16
    const int a_c  = (tid & 15) * 4;   // k offset within tile (float4 granule)
    const int a_r0 = tid >> 4;         // row base (0..15)

    // B-stage mapping: fixed n per thread, k-octets {bk0, bk0+32}
    const int bn_ = tid & 63;              // n within tile
    const int bk0 = (tid >> 6) * 8;        // 0,8,16,24

    // wave / lane decomposition for MFMA: 4 waves stacked in m (32 rows each)
    const int lane = tid & 63;
    const int wid  = tid >> 6;
    const int wm = wid * 32;
    const int lm = lane & 15;
    const int lk = (lane >> 4) * 8;

    const int*    qbase  = qw + (size_t)e * IN * OUT + n0 + bn_;
    const float2* szbase = (const float2*)snz + (size_t)e * G * OUT + n0 + bn_;

    const int kbeg = kh * KCH;
    const int kend = kbeg + KCH;

    for (int k0 = kbeg; k0 < kend; k0 += BK) {
        // ---- stage A: x fp32 -> bf16 LDS, zero-pad invalid rows ----
#pragma unroll
        for (int it = 0; it < 8; ++it) {
            const int r   = a_r0 + it * 16;
            const int row = row0 + r;
            float4 v = {0.f, 0.f, 0.f, 0.f};
            if (row < b1)
                v = *(const float4*)(x + (size_t)row * IN + k0 + a_c);
            union { unsigned long long u; __hip_bfloat162 h2[2]; } pa;
            pa.h2[0] = __float22bfloat162_rn(float2{v.x, v.y});
            pa.h2[1] = __float22bfloat162_rn(float2{v.z, v.w});
            *(unsigned long long*)&As[r][a_c] = pa.u;
        }

        // ---- stage B: int4(as int32) dequant -> bf16, transposed LDS ----
        const int g = k0 >> 6;                 // k0 / GS
        const float2 sz = szbase[(size_t)g * OUT];
        const float s = sz.x;
        const float c = sz.y - 8.0f * s;       // fold (q-8)*s+z -> q*s+c
#pragma unroll
        for (int p = 0; p < 2; ++p) {
            const int k8 = bk0 + p * 32;
            const int* qp = qbase + (size_t)(k0 + k8) * OUT;
            float f[8];
#pragma unroll
            for (int j = 0; j < 8; ++j) {
                const int q = qp[(size_t)j * OUT];   // coalesced across lanes (n-contig)
                f[j] = (float)q * s + c;
            }
            union { short8 v; __hip_bfloat162 h2[4]; } pb;
#pragma unroll
            for (int j = 0; j < 4; ++j)
                pb.h2[j] = __float22bfloat162_rn(float2{f[2 * j], f[2 * j + 1]});
            *(short8*)&Bs[bn_][k8] = pb.v;           // one ds_write_b128
        }

        __syncthreads();

        // ---- MFMA over the K-tile ----
#pragma unroll
        for (int ks = 0; ks < BK; ks += 32) {
            short8 af[2], bfr[4];
#pragma unroll
            for (int i = 0; i < 2; ++i)
                af[i] = *(const short8*)&As[wm + i * 16 + lm][ks + lk];
#pragma unroll
            for (int j = 0; j < 4; ++j)
                bfr[j] = *(const short8*)&Bs[j * 16 + lm][ks + lk];
#pragma unroll
            for (int i = 0; i < 2; ++i)
#pragma unroll
                for (int j = 0; j < 4; ++j)
                    acc[i][j] = __builtin_amdgcn_mfma_f32_16x16x32_bf16(
                        af[i], bfr[j], acc[i][j], 0, 0, 0);
        }

        __syncthreads();
    }

    // ---- epilogue: C/D layout col=lane&15, row=(lane>>4)*4+reg ----
    // K-split partial sums -> fp32 atomicAdd into memset-zero out
    const int lq = (lane >> 4) * 4;
#pragma unroll
    for (int i = 0; i < 2; ++i) {
#pragma unroll
        for (int r = 0; r < 4; ++r) {
            const int row = row0 + wm + i * 16 + lq + r;
            if (row < b1) {
                float* op = out + (size_t)row * OUT + n0 + lm;
#pragma unroll
                for (int j = 0; j < 4; ++j)
                    atomicAdd(op + j * 16, acc[i][j][r]);
            }
        }
    }
}

extern "C" void kernel_launch(void* const* d_in, const int* in_sizes, int n_in,
                              void* d_out, int out_size, void* d_ws, size_t ws_size,
                              hipStream_t stream) {
    const float* x   = (const float*)d_in[0];
    const int*   qw  = (const int*)d_in[1];
    const float* snz = (const float*)d_in[2];
    const int*   tpe = (const int*)d_in[3];
    float* out = (float*)d_out;

    // out is poisoned 0xAA before every launch; k-split accumulates via atomics
    hipMemsetAsync(out, 0, (size_t)out_size * sizeof(float), stream);

    dim3 grid(OUT / BN, T / BM, NE * KSPLIT);   // 32 x 16 x 16
    hqq_grouped_gemm<<<grid, 256, 0, stream>>>(x, qw, snz, tpe, out);
}

// Round 3
// 267.971 us; speedup vs baseline: 1.3766x; 1.1250x over previous
//
#include <hip/hip_runtime.h>
#include <hip/hip_bf16.h>

// Problem constants (match reference)
constexpr int NE  = 8;     // experts
constexpr int T   = 2048;  // tokens
constexpr int IN  = 2048;  // reduction dim
constexpr int OUT = 2048;  // output dim
constexpr int GS  = 64;    // quant group size
constexpr int G   = IN / GS;

// Tile config
constexpr int BM = 128;
constexpr int BN = 64;
constexpr int BK = 64;            // == GS: one scale/zero per K-tile
constexpr int KSPLIT = 2;
constexpr int KCH = IN / KSPLIT;  // 1024
constexpr int LDB = BK + 8;       // pad -> 2-way bank aliasing only (free, m136)

using short8  = __attribute__((ext_vector_type(8))) short;
using floatx4 = __attribute__((ext_vector_type(4))) float;

// x fp32 -> bf16 pre-pass (x is the GEMM A operand; 16.8MB read / 8.4MB write)
__global__ __launch_bounds__(256)
void cvt_x_bf16(const float* __restrict__ x, __hip_bfloat16* __restrict__ xb) {
    const int i = (blockIdx.x * 256 + threadIdx.x) * 4;
    const float4 v = *(const float4*)(x + i);
    union { unsigned long long u; __hip_bfloat162 h2[2]; } p;
    p.h2[0] = __float22bfloat162_rn(float2{v.x, v.y});
    p.h2[1] = __float22bfloat162_rn(float2{v.z, v.w});
    *(unsigned long long*)(xb + i) = p.u;
}

__global__ __launch_bounds__(256, 4)
void hqq_grouped_gemm(const __hip_bfloat16* __restrict__ xb,
                      const int*   __restrict__ qw,
                      const float* __restrict__ snz,   // [E][G][OUT][2]
                      const int*   __restrict__ tpe,   // [E]
                      float* __restrict__ out) {
    const int tid = threadIdx.x;
    const int e   = blockIdx.z >> 1;
    const int kh  = blockIdx.z & 1;
    const int tm  = blockIdx.y;
    const int n0  = blockIdx.x * BN;

    // expert row bounds from prefix sum (wave-uniform, L2-hot)
    int b0 = 0;
    for (int i = 0; i < NE; ++i) {
        int c = tpe[i];
        if (i < e) b0 += c;
    }
    const int b1 = b0 + tpe[e];
    const int row0 = b0 + tm * BM;
    if (row0 >= b1) return;

    // B-only LDS (A-fragments come straight from L2-hot bf16 x)
    __shared__ __hip_bfloat16 Bs[BN][LDB];

    floatx4 acc[2][4];
#pragma unroll
    for (int i = 0; i < 2; ++i)
#pragma unroll
        for (int j = 0; j < 4; ++j)
            acc[i][j] = (floatx4){0.f, 0.f, 0.f, 0.f};

    // B-stage mapping: fixed n per thread, k-octets {bk0, bk0+32}
    const int bn_ = tid & 63;
    const int bk0 = (tid >> 6) * 8;   // 0,8,16,24 per wave

    // MFMA decomposition: 4 waves stacked in m (32 rows each)
    const int lane = tid & 63;
    const int wid  = tid >> 6;
    const int wm = wid * 32;
    const int lm = lane & 15;
    const int lk = (lane >> 4) * 8;

    const int*    qbase  = qw + (size_t)e * IN * OUT + n0 + bn_;
    const float2* szbase = (const float2*)snz + (size_t)e * G * OUT + n0 + bn_;

    const int kbeg  = kh * KCH;
    const int ntile = KCH / BK;

    // ---- register prefetch state: 16 int4-codes + scale/zero ----
    int    qv[16];
    float2 szv;

    // issue all loads for the K-tile at k0 (no waits here; pure issue)
    auto issue = [&](int k0) {
        szv = szbase[(size_t)(k0 >> 6) * OUT];
#pragma unroll
        for (int p = 0; p < 2; ++p) {
            const int* qp = qbase + (size_t)(k0 + bk0 + p * 32) * OUT;
#pragma unroll
            for (int j = 0; j < 8; ++j)
                qv[p * 8 + j] = qp[(size_t)j * OUT];
        }
    };

    issue(kbeg);   // prime the pipeline

    for (int t = 0; t < ntile; ++t) {
        const int k0 = kbeg + t * BK;

        // ---- dequant regs (tile t) -> LDS ----
        const float s = szv.x;
        const float c = szv.y - 8.0f * s;   // (q-8)*s+z == q*s+c
#pragma unroll
        for (int p = 0; p < 2; ++p) {
            union { short8 v; __hip_bfloat162 h2[4]; } pb;
#pragma unroll
            for (int j = 0; j < 4; ++j) {
                const float f0 = (float)qv[p * 8 + 2 * j]     * s + c;
                const float f1 = (float)qv[p * 8 + 2 * j + 1] * s + c;
                pb.h2[j] = __float22bfloat162_rn(float2{f0, f1});
            }
            *(short8*)&Bs[bn_][bk0 + p * 32] = pb.v;   // ds_write_b128
        }

        __syncthreads();   // barrier1: Bs visible (qv already consumed)

        // ---- issue prefetch for tile t+1: stays in flight through MFMA,
        //      drained at barrier2 (vmcnt0-before-barrier) after MFMA ----
        const int kn = (t + 1 < ntile) ? k0 + BK : k0;   // last iter: L2-hot reload
        issue(kn);

        // ---- MFMA over the K-tile; A-frags direct from global (L2) ----
#pragma unroll
        for (int ks = 0; ks < BK; ks += 32) {
            short8 af[2], bfr[4];
#pragma unroll
            for (int i = 0; i < 2; ++i) {
                const int row = row0 + wm + i * 16 + lm;
                const int rr  = row < b1 ? row : (b1 - 1);  // clamp: garbage rows never stored
                af[i] = *(const short8*)(xb + (size_t)rr * IN + k0 + ks + lk);
            }
#pragma unroll
            for (int j = 0; j < 4; ++j)
                bfr[j] = *(const short8*)&Bs[j * 16 + lm][ks + lk];
#pragma unroll
            for (int i = 0; i < 2; ++i)
#pragma unroll
                for (int j = 0; j < 4; ++j)
                    acc[i][j] = __builtin_amdgcn_mfma_f32_16x16x32_bf16(
                        af[i], bfr[j], acc[i][j], 0, 0, 0);
        }

        __syncthreads();   // barrier2: Bs free for rewrite; drains prefetch
    }

    // ---- epilogue: C/D layout col=lane&15, row=(lane>>4)*4+reg ----
    const int lq = (lane >> 4) * 4;
#pragma unroll
    for (int i = 0; i < 2; ++i) {
#pragma unroll
        for (int r = 0; r < 4; ++r) {
            const int row = row0 + wm + i * 16 + lq + r;
            if (row < b1) {
                float* op = out + (size_t)row * OUT + n0 + lm;
#pragma unroll
                for (int j = 0; j < 4; ++j)
                    atomicAdd(op + j * 16, acc[i][j][r]);
            }
        }
    }
}

extern "C" void kernel_launch(void* const* d_in, const int* in_sizes, int n_in,
                              void* d_out, int out_size, void* d_ws, size_t ws_size,
                              hipStream_t stream) {
    const float* x   = (const float*)d_in[0];
    const int*   qw  = (const int*)d_in[1];
    const float* snz = (const float*)d_in[2];
    const int*   tpe = (const int*)d_in[3];
    float* out = (float*)d_out;
    __hip_bfloat16* xb = (__hip_bfloat16*)d_ws;   // needs T*IN*2 = 8.4 MB of ws

    // out is poisoned 0xAA; k-split accumulates via atomics into zeroed out
    hipMemsetAsync(out, 0, (size_t)out_size * sizeof(float), stream);

    cvt_x_bf16<<<(T * IN) / (256 * 4), 256, 0, stream>>>(x, xb);

    dim3 grid(OUT / BN, T / BM, NE * KSPLIT);   // 32 x 16 x 16
    hqq_grouped_gemm<<<grid, 256, 0, stream>>>(xb, qw, snz, tpe, out);
}